// Round 15
// baseline (81.156 us; speedup 1.0000x reference)
//
#include <hip/hip_runtime.h>
#include <hip/hip_bf16.h>
#include <cstddef>

// Problem constants
#define BB 8
#define CC 64
#define OO 64
#define HH 256
#define WW 256
#define MODES 16
#define NXCD 8

// Workspace layout (float offsets)
//  [0)       pft [B*C][4][2][16][2]  131072   (per-stripe partial spectra)
//  [131072)  g   [2][B][O][256]      262144
#define WS_PFT 0
#define WS_G   131072

#define TWO_PI 6.2831853071795864769f

typedef __attribute__((ext_vector_type(8)))  short short8v;
typedef __attribute__((ext_vector_type(16))) float f32x16;
typedef __attribute__((ext_vector_type(2)))  float f32x2;   // native vector:
// HIP's float2 is a HIP_vector_type CLASS -> rejected by
// __builtin_nontemporal_store (round-14 compile error). ext_vector works.

// f32 -> bf16 bits via HIP builtin (RNE). NO inline asm (round-7 lesson).
__device__ __forceinline__ short f2bf_s(float v) {
    return (short)__builtin_bit_cast(unsigned short, __float2bfloat16(v));
}

// XCD-affinity swizzle — used ONLY in k_final (its blocks share per-batch
// gx/gy tables -> L2 reuse; k1/k2 blocks share nothing, r12 showed null).
__device__ __forceinline__ int xcd_swz(int bid, int nwg) {
    return (bid & (NXCD - 1)) * (nwg / NXCD) + (bid >> 3);
}

// ---------------------------------------------------------------------------
// K1: grid = B*C*4. Block j of slice bc handles rows [j*64, j*64+64).
// One pass produces BOTH 16-mode partial spectra (DFT linear in stripes).
// r13 structure (validated): LDS row-partials reduced once in parallel;
// strided conflict-free DFT-tail reads.
__global__ void k_means_dft(const float* __restrict__ x,
                            float* __restrict__ pft) { // [512][4][2][16][2]
    const int blk = blockIdx.x;                  // bc*4 + j
    const int bc  = blk >> 2;
    const int j   = blk & 3;
    const int t   = threadIdx.x;
    const int wave = t >> 6;
    const int lane = t & 63;
    const float* xs = x + (size_t)bc * (HH * WW);

    __shared__ float rowp[64][65];   // [row-in-block][lane] partials (+pad)
    __shared__ float colsum[4][WW];
    __shared__ float cs[WW];
    __shared__ float rm[64];

    float c0 = 0.f, c1 = 0.f, c2 = 0.f, c3 = 0.f;
    const int rbase = wave * 16;
    const int h0 = j * 64 + rbase;
    #pragma unroll
    for (int r = 0; r < 16; ++r) {
        const float4 v = *reinterpret_cast<const float4*>(
            xs + (size_t)(h0 + r) * WW + lane * 4);
        c0 += v.x; c1 += v.y; c2 += v.z; c3 += v.w;
        rowp[rbase + r][lane] = (v.x + v.y) + (v.z + v.w);
    }
    colsum[wave][lane * 4 + 0] = c0;
    colsum[wave][lane * 4 + 1] = c1;
    colsum[wave][lane * 4 + 2] = c2;
    colsum[wave][lane * 4 + 3] = c3;
    __syncthreads();

    {
        const int row = t >> 2;
        const int q   = t & 3;
        float s = 0.f;
        #pragma unroll
        for (int i = 0; i < 16; ++i) s += rowp[row][q * 16 + i];
        s += __shfl_xor(s, 1, 64);
        s += __shfl_xor(s, 2, 64);
        if (q == 0) rm[row] = s * (1.0f / WW);
    }
    cs[t] = (colsum[0][t] + colsum[1][t]) + (colsum[2][t] + colsum[3][t]);
    __syncthreads();

    const int k   = t >> 4;
    const int sub = t & 15;
    const float wk = TWO_PI * (float)k / 256.0f;

    float cre = 0.f, cim = 0.f;
    #pragma unroll
    for (int i = 0; i < 16; ++i) {
        const int w = i * 16 + sub;
        float s, c;
        sincosf(wk * (float)w, &s, &c);
        cre += cs[w] * c;
        cim -= cs[w] * s;
    }
    float rre = 0.f, rim = 0.f;
    #pragma unroll
    for (int i = 0; i < 4; ++i) {
        const int r = i * 16 + sub;
        float s, c;
        sincosf(wk * (float)(j * 64 + r), &s, &c);
        rre += rm[r] * c;
        rim -= rm[r] * s;
    }
    #pragma unroll
    for (int m = 1; m < 16; m <<= 1) {
        cre += __shfl_xor(cre, m, 64);
        cim += __shfl_xor(cim, m, 64);
        rre += __shfl_xor(rre, m, 64);
        rim += __shfl_xor(rim, m, 64);
    }
    if (sub == 0) {
        float* p = pft + (((size_t)blk * 2 + 0) * 16 + k) * 2;
        p[0] = rre; p[1] = rim;
        p += 32;
        p[0] = cre; p[1] = cim;
    }
}

// ---------------------------------------------------------------------------
// K2: fused modemix+synth, grid = 2*B*O = 1024 blocks (one per (br,b,o)).
__global__ void k_mixsynth(const float* __restrict__ pft,
                           const float* __restrict__ wxr, const float* __restrict__ wxi,
                           const float* __restrict__ wyr, const float* __restrict__ wyi,
                           const float* __restrict__ mb,
                           float* __restrict__ g) {
    const int blk = blockIdx.x;          // (br*8 + b)*64 + o
    const int bb  = blk >> 6;
    const int br  = bb >> 3;
    const int b   = bb & 7;
    const int o   = blk & 63;
    const int t   = threadIdx.x;
    const int k   = t & 15;
    const int cg  = t >> 4;
    const int wave = t >> 6;
    const int lane = t & 63;

    const float* wr = br ? wyr : wxr;
    const float* wi = br ? wyi : wxi;
    const float norm = br ? (1.0f / (16.0f * 256.0f)) : (1.0f / 16.0f);

    float are = 0.f, aim = 0.f;
    #pragma unroll
    for (int cc = 0; cc < 4; ++cc) {
        const int c = cg * 4 + cc;
        float re = 0.f, im = 0.f;
        #pragma unroll
        for (int j = 0; j < 4; ++j) {
            const float* p = pft +
                ((((size_t)(b * 64 + c) * 4 + j) * 2 + br) * 16 + k) * 2;
            re += p[0]; im += p[1];
        }
        re *= norm; im *= norm;
        const float wrv = wr[(c * OO + o) * MODES + k];
        const float wiv = wi[(c * OO + o) * MODES + k];
        are += re * wrv - im * wiv;
        aim += re * wiv + im * wrv;
    }
    are += __shfl_xor(are, 16, 64); aim += __shfl_xor(aim, 16, 64);
    are += __shfl_xor(are, 32, 64); aim += __shfl_xor(aim, 32, 64);

    __shared__ float wre[4][16], wim[4][16];
    __shared__ float bre[16], bim[16];
    if (lane < 16) { wre[wave][lane] = are; wim[wave][lane] = aim; }
    __syncthreads();
    if (t < 16) {
        bre[t] = (wre[0][t] + wre[1][t]) + (wre[2][t] + wre[3][t]);
        bim[t] = (wim[0][t] + wim[1][t]) + (wim[2][t] + wim[3][t]);
    }
    __syncthreads();

    float acc = bre[0];
    const float wt = TWO_PI * (float)t / 256.0f;
    #pragma unroll
    for (int kk = 1; kk < MODES; ++kk) {
        float s, c;
        sincosf(wt * (float)kk, &s, &c);
        acc += 2.0f * (bre[kk] * c - bim[kk] * s);
    }
    float v = acc * (1.0f / 16.0f);
    if (br == 0) v += mb[o];
    g[(size_t)blk * 256 + t] = v;
}

// ---------------------------------------------------------------------------
// K3: MFMA epilogue GEMM, pixel-paired f32x2 streams.
// Wave owns a 64-px window; tile A = even pixels (lane n <-> w0+2n),
// tile B = odd pixels (w0+2n+1) — MFMA's N index is just a label, so all
// of {x gather, gy load, out store} become dwordx2 (256B/instr): same
// bytes, HALF the VMEM instructions of r8's dword version (~96 vs ~192).
// Loads staged in two 16-load batches to bound live floats (VGPR<128).
__global__ void __launch_bounds__(256) k_final_mfma(
        const float* __restrict__ x,
        const float* __restrict__ mw,   // [O][C]
        const float* __restrict__ g,    // [2][B][O][256]
        float* __restrict__ out) {
    const int tid  = threadIdx.x;
    const int lane = tid & 63;
    const int wv   = tid >> 6;
    const int blk  = xcd_swz(blockIdx.x, BB * 256);  // b*256 + h
    const int b    = blk >> 8;
    const int h    = blk & 255;
    const int nlo  = lane & 31;
    const int half = lane >> 5;

    const float* gx = g + (size_t)(b * OO) * 256;
    const float* gy = g + (size_t)BB * OO * 256 + (size_t)(b * OO) * 256;

    __shared__ float gxs[OO];
    if (tid < OO) gxs[tid] = gx[tid * 256 + h];

    short8v wf[2][4];
    #pragma unroll
    for (int ot = 0; ot < 2; ++ot) {
        const int o = ot * 32 + nlo;
        const float* wrow = mw + o * CC + 8 * half;
        #pragma unroll
        for (int kb = 0; kb < 4; ++kb) {
            short8v wi;
            #pragma unroll
            for (int i = 0; i < 8; ++i)
                wi[i] = f2bf_s(wrow[kb * 16 + i]);
            wf[ot][kb] = wi;
        }
    }
    __syncthreads();

    const float* xb = x + (size_t)b * CC * (HH * WW) + (size_t)h * WW;
    float*       ob = out + (size_t)b * OO * (HH * WW) + (size_t)h * WW;

    const int w0 = wv * 64;          // 64-px window; pairs via 2*nlo

    // Gather both tiles as f32x2, two batches of 16 dwordx2 loads
    // (128B/lane in flight per batch — same bytes-MLP as r8's flat 32).
    short8v xhA[4], xhB[4];
    #pragma unroll
    for (int batch = 0; batch < 2; ++batch) {
        f32x2 xv[16];
        #pragma unroll
        for (int k2 = 0; k2 < 2; ++k2)
            #pragma unroll
            for (int i = 0; i < 8; ++i) {
                const int c = (batch * 2 + k2) * 16 + 8 * half + i;
                xv[k2 * 8 + i] = *reinterpret_cast<const f32x2*>(
                    xb + (size_t)c * (HH * WW) + w0 + 2 * nlo);
            }
        #pragma unroll
        for (int k2 = 0; k2 < 2; ++k2) {
            short8v xa, xbv;
            #pragma unroll
            for (int i = 0; i < 8; ++i) {
                xa[i]  = f2bf_s(xv[k2 * 8 + i][0]);
                xbv[i] = f2bf_s(xv[k2 * 8 + i][1]);
            }
            xhA[batch * 2 + k2] = xa;
            xhB[batch * 2 + k2] = xbv;
        }
    }

    f32x16 accA, accB;

    #pragma unroll
    for (int ot = 0; ot < 2; ++ot) {
        #pragma unroll
        for (int i = 0; i < 16; ++i) { accA[i] = 0.f; accB[i] = 0.f; }
        #pragma unroll
        for (int kb = 0; kb < 4; ++kb) {
            accA = __builtin_amdgcn_mfma_f32_32x32x16_bf16(wf[ot][kb], xhA[kb], accA, 0, 0, 0);
            accB = __builtin_amdgcn_mfma_f32_32x32x16_bf16(wf[ot][kb], xhB[kb], accB, 0, 0, 0);
        }
        // epilogue: o = ot*32 + (r&3) + 8*(r>>2) + 4*half; paired pixels
        // w0+2nlo (A) and w0+2nlo+1 (B) -> one f32x2 load + one f32x2 store.
        #pragma unroll
        for (int r = 0; r < 16; ++r) {
            const int o = ot * 32 + (r & 3) + 8 * (r >> 2) + 4 * half;
            const f32x2 gyv = *reinterpret_cast<const f32x2*>(
                gy + o * 256 + w0 + 2 * nlo);
            f32x2 v;
            v[0] = accA[r] + gxs[o] + gyv[0];
            v[1] = accB[r] + gxs[o] + gyv[1];
            __builtin_nontemporal_store(v, reinterpret_cast<f32x2*>(
                ob + (size_t)o * (HH * WW) + w0 + 2 * nlo));
        }
    }
}

// ---------------------------------------------------------------------------
extern "C" void kernel_launch(void* const* d_in, const int* in_sizes, int n_in,
                              void* d_out, int out_size, void* d_ws, size_t ws_size,
                              hipStream_t stream) {
    const float* x    = (const float*)d_in[0];
    const float* wxr  = (const float*)d_in[1];
    const float* wxi  = (const float*)d_in[2];
    const float* wyr  = (const float*)d_in[3];
    const float* wyi  = (const float*)d_in[4];
    const float* mixw = (const float*)d_in[5];
    const float* mixb = (const float*)d_in[6];
    float* out = (float*)d_out;
    float* ws  = (float*)d_ws;

    float* pft = ws + WS_PFT;
    float* g   = ws + WS_G;

    k_means_dft<<<BB * CC * 4, 256, 0, stream>>>(x, pft);
    k_mixsynth<<<2 * BB * OO, 256, 0, stream>>>(pft, wxr, wxi, wyr, wyi, mixb, g);
    k_final_mfma<<<BB * 256, 256, 0, stream>>>(x, mixw, g, out);
}